// Round 2
// baseline (238.179 us; speedup 1.0000x reference)
//
#include <hip/hip_runtime.h>
#include <hip/hip_bf16.h>

typedef __attribute__((ext_vector_type(4)))  float f32x4;
typedef __attribute__((ext_vector_type(16))) float f32x16;
typedef __attribute__((ext_vector_type(8)))  short bf16x8;

#define LOG2E 1.44269504088896340736f

// native v_exp_f32 (1 instr, ~1 ulp); plain exp2f lowers to precise OCML (~30 cyc).
#if __has_builtin(__builtin_amdgcn_exp2f)
static __device__ __forceinline__ float exp2_native(float x) {
  return __builtin_amdgcn_exp2f(x);
}
#else
extern "C" __device__ float __ocml_native_exp2_f32(float);
static __device__ __forceinline__ float exp2_native(float x) {
  return __ocml_native_exp2_f32(x);
}
#endif

// bf16 truncation pack: low ushort <- a, high ushort <- b (1x v_perm_b32).
static __device__ __forceinline__ unsigned int pack_trunc_f(float a, float b) {
  return __builtin_amdgcn_perm(__float_as_uint(b), __float_as_uint(a), 0x07060302);
}

// async global->LDS, 16B/lane: LDS dest = wave-uniform base + lane*16 (HW adds)
typedef const __attribute__((address_space(1))) unsigned int gu32;
typedef __attribute__((address_space(3))) unsigned int lu32;
static __device__ __forceinline__ void gload_lds16(const void* g, void* l) {
  __builtin_amdgcn_global_load_lds((gu32*)g, (lu32*)l, 16, 0, 0);
}

// ---------------------------------------------------------------------------
// proj: y = x(32768x64) * K^T(64x80) via MFMA 16x16x32. Block=256thr/4 waves.
// g-columns pre-scaled by log2(e) so attn can use native exp2 directly.
// h stored per 128-key tile as [c][136] bf16 (8-slot pad, garbage) with keys
// at PERMUTED position kpos = bitswap2<->3(key&127): attn's S^T C-layout ==
// PV A-layout with contiguous B-frags. (Stride 136 = 68 words == 4 mod 32:
// 8-lane b128 phases hit distinct banks -> 0 conflicts, measured R4/R5.)
// Also zeroes the 256 split-K completion counters (block 0) -- visible to
// attn via the kernel boundary (stream-ordered, device-wide writeback).
// ---------------------------------------------------------------------------
__global__ __launch_bounds__(256) void proj_kernel(
    const float* __restrict__ x, const float* __restrict__ kf,
    const float* __restrict__ kg, const float* __restrict__ kh,
    unsigned short* __restrict__ f_b, unsigned short* __restrict__ g_b,
    unsigned short* __restrict__ h_p, int* __restrict__ cnt)
{
  __shared__ unsigned short Kt[80*72];
  const int t = threadIdx.x, blk = blockIdx.x;

  if (blk == 0) cnt[t] = 0;   // 256 counters, one per (qb,b)

  #pragma unroll
  for (int r = 0; r < 20; ++r) {
    int idx = r*256 + t;                 // 5120 = 80x64
    int o = idx >> 6, c = idx & 63;
    float v = (o < 8) ? kf[c*8 + o]
            : (o < 16) ? kg[c*8 + (o-8)] * LOG2E
            : kh[c*64 + (o-16)];
    Kt[o*72 + c] = (unsigned short)(__float_as_uint(v) >> 16);
  }
  __syncthreads();

  const int w = t >> 6, lane = t & 63, l15 = lane & 15, quad = lane >> 4;
  const int Rbase = blk*64 + w*16;
  const int R = Rbase + l15;

  bf16x8 af[2];
  #pragma unroll
  for (int kk = 0; kk < 2; ++kk) {
    const float* xp = x + (long)R*64 + kk*32 + quad*8;
    float4 v0 = *(const float4*)xp;
    float4 v1 = *(const float4*)(xp + 4);
    union { unsigned int u[4]; bf16x8 v; } p;
    p.u[0] = pack_trunc_f(v0.x, v0.y);
    p.u[1] = pack_trunc_f(v0.z, v0.w);
    p.u[2] = pack_trunc_f(v1.x, v1.y);
    p.u[3] = pack_trunc_f(v1.z, v1.w);
    af[kk] = p.v;
  }

  f32x4 acc[5];
  #pragma unroll
  for (int nt = 0; nt < 5; ++nt) { f32x4 z = {}; acc[nt] = z; }

  #pragma unroll
  for (int nt = 0; nt < 5; ++nt)
    #pragma unroll
    for (int kk = 0; kk < 2; ++kk) {
      bf16x8 bfv = *(const bf16x8*)&Kt[(nt*16 + l15)*72 + kk*32 + quad*8];
      acc[nt] = __builtin_amdgcn_mfma_f32_16x16x32_bf16(af[kk], bfv, acc[nt], 0, 0, 0);
    }

  const int bt = Rbase >> 12;
  const int kt = (Rbase >> 7) & 31;
  const int base = ((blk & 1) << 6) + (w << 4);
  // permuted store position: swap bits 2<->3 of (base + 4*quad + rr)
  const int pi = base + ((quad & 1) << 3) + (((quad >> 1) & 1) << 2);

  #pragma unroll
  for (int rr = 0; rr < 4; ++rr) {
    const int nq = (Rbase + quad*4 + rr) & 4095;
    unsigned short v = (unsigned short)(__float_as_uint(acc[0][rr]) >> 16);
    if (l15 < 8) f_b[((long)bt*4096 + nq)*8 + l15] = v;
    else         g_b[((long)bt*4096 + nq)*8 + (l15 - 8)] = v;
  }
  #pragma unroll
  for (int nt = 1; nt < 5; ++nt) {
    const int c = (nt - 1)*16 + l15;
    uint2 v;
    v.x = pack_trunc_f(acc[nt][0], acc[nt][1]);
    v.y = pack_trunc_f(acc[nt][2], acc[nt][3]);
    *(uint2*)(h_p + ((long)(bt*32 + kt)*64 + c)*136 + pi) = v;
  }
}

// ---------------------------------------------------------------------------
// attn: split-K flash attention (no-max softmax; |s| << 1 by construction)
// WITH fused last-block-wins combine.
// Grid (32 qtiles, 8 batch, 4 splits); block = 256 thr = 4 waves;
// one q-group (32 queries) per wave. Double-buffered LDS staging via
// global_load_lds, one barrier per 128-key tile.
// After writing po/pl partials: device-scope release fence -> atomicAdd on
// the (qb,b) counter; the 4th arriving block re-reads all splits' partials
// (L3-resident, writers' fences made them visible past the per-XCD L2s)
// and performs the combine: out = gamma * (sum po) / (sum pl) + x.
// Winner identity is timing-dependent; the combined VALUE is not (sum of 4
// fixed partials) -> G16-safe. Math is bit-identical to the old
// combine_kernel (f32 accumulate of bf16 partials, fmaf epilogue).
// ---------------------------------------------------------------------------
__global__ __launch_bounds__(256, 4) void attn_kernel(
    const unsigned short* __restrict__ f_b, const unsigned short* __restrict__ g_b,
    const unsigned short* __restrict__ h_p, unsigned short* __restrict__ po,
    float* __restrict__ pl, int* __restrict__ cnt,
    const float* __restrict__ x, const float* __restrict__ gamma_p,
    float* __restrict__ out)
{
  // buf = h tile [64][136] (17408 B) then f tile [128][8] (2048 B)
  __shared__ unsigned short bufs[2][9728];
  __shared__ int sflag;

  const int t = threadIdx.x;
  const int w = t >> 6, lane = t & 63, l31 = lane & 31, a = lane >> 5;
  const int qb = blockIdx.x, b = blockIdx.y, sp = blockIdx.z;
  const int q0w = qb*128 + w*32;

  // g B-frag: n = q = l31, k = a*8+j ; real only at a=0 (K=8 zero-padded)
  bf16x8 gfv;
  {
    bf16x8 gv = *(const bf16x8*)(g_b + ((long)b*4096 + q0w + l31)*8);
    bf16x8 z = {};
    gfv = (a == 0) ? gv : z;
  }

  f32x16 oacc[2];
  { f32x16 z = {}; oacc[0] = z; oacc[1] = z; }
  float l_run = 0.f;

  const char* hp_b = (const char*)h_p + (long)b*32*17408;
  const char* fb_b = (const char*)f_b + (long)b*4096*16;

  // stage tile (sp*8 + kt) into bufs[bi]; 19456 B split as 1 KiB chunks
  // over 4 waves (wave w, step i -> byte off i*4096 + w*1024).
  auto stage = [&](int bi, int kt) {
    const char* hsrc = hp_b + (long)kt*17408;
    const char* fsrc = fb_b + (long)kt*2048;
    char* dst = (char*)&bufs[bi][0];
    #pragma unroll
    for (int i = 0; i < 5; ++i) {
      const int off = i*4096 + w*1024;
      if (off < 19456) {
        const char* src = (off < 17408) ? (hsrc + off) : (fsrc + (off - 17408));
        gload_lds16(src + lane*16, dst + off);
      }
    }
  };

  stage(0, sp*8);

  for (int ktl = 0; ktl < 8; ++ktl) {
    __syncthreads();                     // drains tile-ktl loads; protects reuse
    if (ktl < 7) stage((ktl + 1) & 1, sp*8 + ktl + 1);

    const unsigned short* hts = &bufs[ktl & 1][0];
    const unsigned short* fts = &bufs[ktl & 1][8704];

    #pragma unroll
    for (int mt = 0; mt < 4; ++mt) {
      // S^T sub-tile: keys mt*32.. (storage order) x 32 queries
      bf16x8 afv = *(const bf16x8*)&fts[(mt*32 + l31)*8];
      f32x16 zz = {};
      f32x16 sc = __builtin_amdgcn_mfma_f32_32x32x16_bf16(afv, gfv, zz, 0, 0, 0);

      #pragma unroll
      for (int half = 0; half < 2; ++half) {
        const int s = mt*2 + half;       // PV K-step: contraction k in [16s,16s+16)
        bf16x8 bh0 = *(const bf16x8*)&hts[(l31)*136      + s*16 + a*8];
        bf16x8 bh1 = *(const bf16x8*)&hts[(32 + l31)*136 + s*16 + a*8];
        union { unsigned int u[4]; bf16x8 v; } ap;
        #pragma unroll
        for (int j = 0; j < 4; ++j) {
          float ea = exp2_native(sc[half*8 + 2*j]);      // g pre-scaled by log2e
          float eb = exp2_native(sc[half*8 + 2*j + 1]);
          l_run += ea;
          l_run += eb;
          ap.u[j] = pack_trunc_f(ea, eb);
        }
        oacc[0] = __builtin_amdgcn_mfma_f32_32x32x16_bf16(ap.v, bh0, oacc[0], 0, 0, 0);
        oacc[1] = __builtin_amdgcn_mfma_f32_32x32x16_bf16(ap.v, bh1, oacc[1], 0, 0, 0);
      }
    }
  }

  const long sb = (long)sp*8 + b;
  // a=0/a=1 lane halves hold disjoint key-rows of the same query l31
  float l = l_run + __shfl_xor(l_run, 32);
  if (lane < 32) pl[(sb << 12) + q0w + l31] = l;
  // partial o: C col = c = nt*32+l31, row q = (r&3)+8*(r>>2)+4a
  unsigned short* pob = po + ((sb << 12) + q0w)*64;
  #pragma unroll
  for (int nt = 0; nt < 2; ++nt)
    #pragma unroll
    for (int r = 0; r < 16; ++r) {
      const int q = (r & 3) + 8*(r >> 2) + 4*a;
      pob[(long)q*64 + nt*32 + l31] =
          (unsigned short)(__float_as_uint(oacc[nt][r]) >> 16);
    }

  // ---- last-block-wins combine for queries [qb*128, qb*128+128) of b ----
  __threadfence();                       // release: partials -> coherence point
  if (t == 0) {
    int old = atomicAdd(&cnt[qb*8 + b], 1);
    sflag = (old == 3);
  }
  __syncthreads();
  if (!sflag) return;
  __threadfence();                       // acquire side before reading partials

  const int q = qb*128 + (t >> 1);       // 128 queries, 2 threads per query
  const int c0 = (t & 1) * 32;           // 32 channels per thread
  float lsum = 0.f;
  float o[32];
  #pragma unroll
  for (int i = 0; i < 32; ++i) o[i] = 0.f;
  #pragma unroll
  for (int s = 0; s < 4; ++s) {
    const long sbb = (long)s*8 + b;
    lsum += pl[(sbb << 12) + q];
    const unsigned short* ps = po + ((sbb << 12) + q)*64 + c0;
    #pragma unroll
    for (int v4 = 0; v4 < 4; ++v4) {
      uint4 v = *(const uint4*)(ps + v4*8);
      const unsigned short* pv = (const unsigned short*)&v;
      #pragma unroll
      for (int i = 0; i < 8; ++i)
        o[v4*8 + i] += __uint_as_float((unsigned int)pv[i] << 16);
    }
  }
  const float scale = gamma_p[0] / lsum;
  const float* xp = x + ((long)b*4096 + q)*64 + c0;
  float* op = out + ((long)b*4096 + q)*64 + c0;
  #pragma unroll
  for (int v4 = 0; v4 < 8; ++v4) {
    float4 xv = *(const float4*)(xp + v4*4);
    float4 r;
    r.x = fmaf(scale, o[v4*4 + 0], xv.x);
    r.y = fmaf(scale, o[v4*4 + 1], xv.y);
    r.z = fmaf(scale, o[v4*4 + 2], xv.z);
    r.w = fmaf(scale, o[v4*4 + 3], xv.w);
    *(float4*)(op + v4*4) = r;
  }
}

extern "C" void kernel_launch(void* const* d_in, const int* in_sizes, int n_in,
                              void* d_out, int out_size, void* d_ws, size_t ws_size,
                              hipStream_t stream) {
  const float* x  = (const float*)d_in[0];
  const float* kf = (const float*)d_in[1];
  const float* kg = (const float*)d_in[2];
  const float* kh = (const float*)d_in[3];
  const float* gamma = (const float*)d_in[4];
  float* out = (float*)d_out;

  char* ws = (char*)d_ws;
  unsigned short* h_p = (unsigned short*)ws;                  // 8*32*64*136*2 = 4,456,448
  unsigned short* f_b = (unsigned short*)(ws + 4456448);      // 524,288
  unsigned short* g_b = (unsigned short*)(ws + 4980736);      // 524,288
  unsigned short* po  = (unsigned short*)(ws + 5505024);      // 4*8*4096*64*2 = 16,777,216
  float*          pl  = (float*)(ws + 22282240);              // 4*8*4096*4 = 524,288
  int*            cnt = (int*)(ws + 22806528);                // 256*4 = 1,024

  proj_kernel<<<512, 256, 0, stream>>>(x, kf, kg, kh, f_b, g_b, h_p, cnt);
  attn_kernel<<<dim3(32, 8, 4), 256, 0, stream>>>(f_b, g_b, h_p, po, pl, cnt,
                                                  x, gamma, out);
}

// Round 3
// 116.088 us; speedup vs baseline: 2.0517x; 2.0517x over previous
//
#include <hip/hip_runtime.h>
#include <hip/hip_bf16.h>

typedef __attribute__((ext_vector_type(4)))  float f32x4;
typedef __attribute__((ext_vector_type(16))) float f32x16;
typedef __attribute__((ext_vector_type(8)))  short bf16x8;

#define LOG2E 1.44269504088896340736f

// native v_exp_f32 (1 instr, ~1 ulp); plain exp2f lowers to precise OCML (~30 cyc).
#if __has_builtin(__builtin_amdgcn_exp2f)
static __device__ __forceinline__ float exp2_native(float x) {
  return __builtin_amdgcn_exp2f(x);
}
#else
extern "C" __device__ float __ocml_native_exp2_f32(float);
static __device__ __forceinline__ float exp2_native(float x) {
  return __ocml_native_exp2_f32(x);
}
#endif

// bf16 truncation pack: low ushort <- a, high ushort <- b (1x v_perm_b32).
static __device__ __forceinline__ unsigned int pack_trunc_f(float a, float b) {
  return __builtin_amdgcn_perm(__float_as_uint(b), __float_as_uint(a), 0x07060302);
}

// async global->LDS, 16B/lane: LDS dest = wave-uniform base + lane*16 (HW adds)
typedef const __attribute__((address_space(1))) unsigned int gu32;
typedef __attribute__((address_space(3))) unsigned int lu32;
static __device__ __forceinline__ void gload_lds16(const void* g, void* l) {
  __builtin_amdgcn_global_load_lds((gu32*)g, (lu32*)l, 16, 0, 0);
}

// ---------------------------------------------------------------------------
// proj: y = x(32768x64) * K^T(64x80) via MFMA 16x16x32. Block=256thr/4 waves.
// g-columns pre-scaled by log2(e) so attn can use native exp2 directly.
// h stored per 128-key tile as [c][136] bf16 (8-slot pad, garbage) with keys
// at PERMUTED position kpos = bitswap2<->3(key&127): attn's S^T C-layout ==
// PV A-layout with contiguous B-frags. (Stride 136 = 68 words == 4 mod 32:
// 8-lane b128 phases hit distinct banks -> 0 conflicts, measured R4/R5.)
// ---------------------------------------------------------------------------
__global__ __launch_bounds__(256) void proj_kernel(
    const float* __restrict__ x, const float* __restrict__ kf,
    const float* __restrict__ kg, const float* __restrict__ kh,
    unsigned short* __restrict__ f_b, unsigned short* __restrict__ g_b,
    unsigned short* __restrict__ h_p)
{
  __shared__ unsigned short Kt[80*72];
  const int t = threadIdx.x, blk = blockIdx.x;

  #pragma unroll
  for (int r = 0; r < 20; ++r) {
    int idx = r*256 + t;                 // 5120 = 80x64
    int o = idx >> 6, c = idx & 63;
    float v = (o < 8) ? kf[c*8 + o]
            : (o < 16) ? kg[c*8 + (o-8)] * LOG2E
            : kh[c*64 + (o-16)];
    Kt[o*72 + c] = (unsigned short)(__float_as_uint(v) >> 16);
  }
  __syncthreads();

  const int w = t >> 6, lane = t & 63, l15 = lane & 15, quad = lane >> 4;
  const int Rbase = blk*64 + w*16;
  const int R = Rbase + l15;

  bf16x8 af[2];
  #pragma unroll
  for (int kk = 0; kk < 2; ++kk) {
    const float* xp = x + (long)R*64 + kk*32 + quad*8;
    float4 v0 = *(const float4*)xp;
    float4 v1 = *(const float4*)(xp + 4);
    union { unsigned int u[4]; bf16x8 v; } p;
    p.u[0] = pack_trunc_f(v0.x, v0.y);
    p.u[1] = pack_trunc_f(v0.z, v0.w);
    p.u[2] = pack_trunc_f(v1.x, v1.y);
    p.u[3] = pack_trunc_f(v1.z, v1.w);
    af[kk] = p.v;
  }

  f32x4 acc[5];
  #pragma unroll
  for (int nt = 0; nt < 5; ++nt) { f32x4 z = {}; acc[nt] = z; }

  #pragma unroll
  for (int nt = 0; nt < 5; ++nt)
    #pragma unroll
    for (int kk = 0; kk < 2; ++kk) {
      bf16x8 bfv = *(const bf16x8*)&Kt[(nt*16 + l15)*72 + kk*32 + quad*8];
      acc[nt] = __builtin_amdgcn_mfma_f32_16x16x32_bf16(af[kk], bfv, acc[nt], 0, 0, 0);
    }

  const int bt = Rbase >> 12;
  const int kt = (Rbase >> 7) & 31;
  const int base = ((blk & 1) << 6) + (w << 4);
  // permuted store position: swap bits 2<->3 of (base + 4*quad + rr)
  const int pi = base + ((quad & 1) << 3) + (((quad >> 1) & 1) << 2);

  #pragma unroll
  for (int rr = 0; rr < 4; ++rr) {
    const int nq = (Rbase + quad*4 + rr) & 4095;
    unsigned short v = (unsigned short)(__float_as_uint(acc[0][rr]) >> 16);
    if (l15 < 8) f_b[((long)bt*4096 + nq)*8 + l15] = v;
    else         g_b[((long)bt*4096 + nq)*8 + (l15 - 8)] = v;
  }
  #pragma unroll
  for (int nt = 1; nt < 5; ++nt) {
    const int c = (nt - 1)*16 + l15;
    uint2 v;
    v.x = pack_trunc_f(acc[nt][0], acc[nt][1]);
    v.y = pack_trunc_f(acc[nt][2], acc[nt][3]);
    *(uint2*)(h_p + ((long)(bt*32 + kt)*64 + c)*136 + pi) = v;
  }
}

// ---------------------------------------------------------------------------
// attn: FULL-K flash attention (no-max softmax; |s| << 1 by construction)
// with direct epilogue -- no split-K, no partials, no cross-block sync.
// Grid (32 qtiles, 8 batch); block = 256 thr = 4 waves; each wave owns 32
// queries over ALL 32 key tiles (4096 keys), so o stays f32 end-to-end and
// the block can normalize + add residual itself:
//   out = gamma * o / l + x
// Double-buffered LDS staging via global_load_lds with ONE barrier per tile:
//   barrier (drains tile-t loads) -> issue tile-t+1 loads into other buffer
//   -> compute tile t (a full compute phase hides the staging latency).
// Occupancy is 1 wave/SIMD (1024 query-waves total) -- R0 A/B showed attn is
// throughput-bound (2->4 waves/SIMD was null), and ILP across the 16
// independent exp2s + compiler pipelining across mt iterations covers the
// remaining latency. No device-scope fences anywhere (R2 lesson: a
// __threadfence() epilogue costs an L2 writeback per block on gfx950).
// ---------------------------------------------------------------------------
__global__ __launch_bounds__(256) void attn_kernel(
    const unsigned short* __restrict__ f_b, const unsigned short* __restrict__ g_b,
    const unsigned short* __restrict__ h_p,
    const float* __restrict__ x, const float* __restrict__ gamma_p,
    float* __restrict__ out)
{
  // buf = h tile [64][136] (17408 B) then f tile [128][8] (2048 B)
  __shared__ unsigned short bufs[2][9728];

  const int t = threadIdx.x;
  const int w = t >> 6, lane = t & 63, l31 = lane & 31, a = lane >> 5;
  const int qb = blockIdx.x, b = blockIdx.y;
  const int q0w = qb*128 + w*32;

  // g B-frag: n = q = l31, k = a*8+j ; real only at a=0 (K=8 zero-padded)
  bf16x8 gfv;
  {
    bf16x8 gv = *(const bf16x8*)(g_b + ((long)b*4096 + q0w + l31)*8);
    bf16x8 z = {};
    gfv = (a == 0) ? gv : z;
  }

  f32x16 oacc[2];
  { f32x16 z = {}; oacc[0] = z; oacc[1] = z; }
  float l_run = 0.f;

  const char* hp_b = (const char*)h_p + (long)b*32*17408;
  const char* fb_b = (const char*)f_b + (long)b*4096*16;

  // stage tile kt into bufs[bi]; 19456 B split as 1 KiB chunks
  // over 4 waves (wave w, step i -> byte off i*4096 + w*1024).
  auto stage = [&](int bi, int kt) {
    const char* hsrc = hp_b + (long)kt*17408;
    const char* fsrc = fb_b + (long)kt*2048;
    char* dst = (char*)&bufs[bi][0];
    #pragma unroll
    for (int i = 0; i < 5; ++i) {
      const int off = i*4096 + w*1024;
      if (off < 19456) {
        const char* src = (off < 17408) ? (hsrc + off) : (fsrc + (off - 17408));
        gload_lds16(src + lane*16, dst + off);
      }
    }
  };

  stage(0, 0);

  for (int ktl = 0; ktl < 32; ++ktl) {
    __syncthreads();                     // drains tile-ktl loads; protects reuse
    if (ktl < 31) stage((ktl + 1) & 1, ktl + 1);

    const unsigned short* hts = &bufs[ktl & 1][0];
    const unsigned short* fts = &bufs[ktl & 1][8704];

    #pragma unroll
    for (int mt = 0; mt < 4; ++mt) {
      // S^T sub-tile: keys mt*32.. (storage order) x 32 queries
      bf16x8 afv = *(const bf16x8*)&fts[(mt*32 + l31)*8];
      f32x16 zz = {};
      f32x16 sc = __builtin_amdgcn_mfma_f32_32x32x16_bf16(afv, gfv, zz, 0, 0, 0);

      #pragma unroll
      for (int half = 0; half < 2; ++half) {
        const int s = mt*2 + half;       // PV K-step: contraction k in [16s,16s+16)
        bf16x8 bh0 = *(const bf16x8*)&hts[(l31)*136      + s*16 + a*8];
        bf16x8 bh1 = *(const bf16x8*)&hts[(32 + l31)*136 + s*16 + a*8];
        union { unsigned int u[4]; bf16x8 v; } ap;
        #pragma unroll
        for (int j = 0; j < 4; ++j) {
          float ea = exp2_native(sc[half*8 + 2*j]);      // g pre-scaled by log2e
          float eb = exp2_native(sc[half*8 + 2*j + 1]);
          l_run += ea;
          l_run += eb;
          ap.u[j] = pack_trunc_f(ea, eb);
        }
        oacc[0] = __builtin_amdgcn_mfma_f32_32x32x16_bf16(ap.v, bh0, oacc[0], 0, 0, 0);
        oacc[1] = __builtin_amdgcn_mfma_f32_32x32x16_bf16(ap.v, bh1, oacc[1], 0, 0, 0);
      }
    }
  }

  // ---- epilogue: out = gamma * o / l + x for this wave's 32 queries ----
  // a=0/a=1 lane halves hold disjoint key-halves of the same query l31:
  // after the xor-32 reduce, lanes q and q+32 both hold query q's total l.
  const float l = l_run + __shfl_xor(l_run, 32);
  const float gamma = gamma_p[0];
  const float* xb = x + ((long)b*4096 + q0w)*64;
  float* ob = out + ((long)b*4096 + q0w)*64;

  #pragma unroll
  for (int r = 0; r < 16; ++r) {
    const int q = (r & 3) + 8*(r >> 2) + 4*a;   // C row for this acc reg
    const float lq = __shfl(l, q);              // lane q holds query q's l
    const float s = gamma / lq;
    #pragma unroll
    for (int nt = 0; nt < 2; ++nt) {
      const long idx = (long)q*64 + nt*32 + l31; // col c = nt*32+l31
      ob[idx] = fmaf(s, oacc[nt][r], xb[idx]);
    }
  }
}

extern "C" void kernel_launch(void* const* d_in, const int* in_sizes, int n_in,
                              void* d_out, int out_size, void* d_ws, size_t ws_size,
                              hipStream_t stream) {
  const float* x  = (const float*)d_in[0];
  const float* kf = (const float*)d_in[1];
  const float* kg = (const float*)d_in[2];
  const float* kh = (const float*)d_in[3];
  const float* gamma = (const float*)d_in[4];
  float* out = (float*)d_out;

  char* ws = (char*)d_ws;
  unsigned short* h_p = (unsigned short*)ws;                  // 8*32*64*136*2 = 4,456,448
  unsigned short* f_b = (unsigned short*)(ws + 4456448);      // 524,288
  unsigned short* g_b = (unsigned short*)(ws + 4980736);      // 524,288

  proj_kernel<<<512, 256, 0, stream>>>(x, kf, kg, kh, f_b, g_b, h_p);
  attn_kernel<<<dim3(32, 8), 256, 0, stream>>>(f_b, g_b, h_p, x, gamma, out);
}

// Round 4
// 109.256 us; speedup vs baseline: 2.1800x; 1.0625x over previous
//
#include <hip/hip_runtime.h>
#include <hip/hip_bf16.h>

typedef __attribute__((ext_vector_type(4)))  float f32x4;
typedef __attribute__((ext_vector_type(16))) float f32x16;
typedef __attribute__((ext_vector_type(8)))  short bf16x8;

#define LOG2E 1.44269504088896340736f

// native v_exp_f32 (1 instr, ~1 ulp); plain exp2f lowers to precise OCML (~30 cyc).
#if __has_builtin(__builtin_amdgcn_exp2f)
static __device__ __forceinline__ float exp2_native(float x) {
  return __builtin_amdgcn_exp2f(x);
}
#else
extern "C" __device__ float __ocml_native_exp2_f32(float);
static __device__ __forceinline__ float exp2_native(float x) {
  return __ocml_native_exp2_f32(x);
}
#endif

// bf16 truncation pack: low ushort <- a, high ushort <- b (1x v_perm_b32).
static __device__ __forceinline__ unsigned int pack_trunc_f(float a, float b) {
  return __builtin_amdgcn_perm(__float_as_uint(b), __float_as_uint(a), 0x07060302);
}

// async global->LDS, 16B/lane: LDS dest = wave-uniform base + lane*16 (HW adds)
typedef const __attribute__((address_space(1))) unsigned int gu32;
typedef __attribute__((address_space(3))) unsigned int lu32;
static __device__ __forceinline__ void gload_lds16(const void* g, void* l) {
  __builtin_amdgcn_global_load_lds((gu32*)g, (lu32*)l, 16, 0, 0);
}

// ---------------------------------------------------------------------------
// proj: y = x(32768x64) * K^T(64x80) via MFMA 16x16x32. Block=256thr/4 waves.
// g-columns pre-scaled by log2(e) so attn can use native exp2 directly.
// h stored per 128-key tile as [c][136] bf16 (8-slot pad, garbage) with keys
// at PERMUTED position kpos = bitswap2<->3(key&127): attn's S^T C-layout ==
// PV A-layout with contiguous B-frags. (Stride 136 = 68 words == 4 mod 32:
// 8-lane b128 phases hit distinct banks -> 0 conflicts, measured R4/R5.)
// ---------------------------------------------------------------------------
__global__ __launch_bounds__(256) void proj_kernel(
    const float* __restrict__ x, const float* __restrict__ kf,
    const float* __restrict__ kg, const float* __restrict__ kh,
    unsigned short* __restrict__ f_b, unsigned short* __restrict__ g_b,
    unsigned short* __restrict__ h_p)
{
  __shared__ unsigned short Kt[80*72];
  const int t = threadIdx.x, blk = blockIdx.x;

  #pragma unroll
  for (int r = 0; r < 20; ++r) {
    int idx = r*256 + t;                 // 5120 = 80x64
    int o = idx >> 6, c = idx & 63;
    float v = (o < 8) ? kf[c*8 + o]
            : (o < 16) ? kg[c*8 + (o-8)] * LOG2E
            : kh[c*64 + (o-16)];
    Kt[o*72 + c] = (unsigned short)(__float_as_uint(v) >> 16);
  }
  __syncthreads();

  const int w = t >> 6, lane = t & 63, l15 = lane & 15, quad = lane >> 4;
  const int Rbase = blk*64 + w*16;
  const int R = Rbase + l15;

  bf16x8 af[2];
  #pragma unroll
  for (int kk = 0; kk < 2; ++kk) {
    const float* xp = x + (long)R*64 + kk*32 + quad*8;
    float4 v0 = *(const float4*)xp;
    float4 v1 = *(const float4*)(xp + 4);
    union { unsigned int u[4]; bf16x8 v; } p;
    p.u[0] = pack_trunc_f(v0.x, v0.y);
    p.u[1] = pack_trunc_f(v0.z, v0.w);
    p.u[2] = pack_trunc_f(v1.x, v1.y);
    p.u[3] = pack_trunc_f(v1.z, v1.w);
    af[kk] = p.v;
  }

  f32x4 acc[5];
  #pragma unroll
  for (int nt = 0; nt < 5; ++nt) { f32x4 z = {}; acc[nt] = z; }

  #pragma unroll
  for (int nt = 0; nt < 5; ++nt)
    #pragma unroll
    for (int kk = 0; kk < 2; ++kk) {
      bf16x8 bfv = *(const bf16x8*)&Kt[(nt*16 + l15)*72 + kk*32 + quad*8];
      acc[nt] = __builtin_amdgcn_mfma_f32_16x16x32_bf16(af[kk], bfv, acc[nt], 0, 0, 0);
    }

  const int bt = Rbase >> 12;
  const int kt = (Rbase >> 7) & 31;
  const int base = ((blk & 1) << 6) + (w << 4);
  // permuted store position: swap bits 2<->3 of (base + 4*quad + rr)
  const int pi = base + ((quad & 1) << 3) + (((quad >> 1) & 1) << 2);

  #pragma unroll
  for (int rr = 0; rr < 4; ++rr) {
    const int nq = (Rbase + quad*4 + rr) & 4095;
    unsigned short v = (unsigned short)(__float_as_uint(acc[0][rr]) >> 16);
    if (l15 < 8) f_b[((long)bt*4096 + nq)*8 + l15] = v;
    else         g_b[((long)bt*4096 + nq)*8 + (l15 - 8)] = v;
  }
  #pragma unroll
  for (int nt = 1; nt < 5; ++nt) {
    const int c = (nt - 1)*16 + l15;
    uint2 v;
    v.x = pack_trunc_f(acc[nt][0], acc[nt][1]);
    v.y = pack_trunc_f(acc[nt][2], acc[nt][3]);
    *(uint2*)(h_p + ((long)(bt*32 + kt)*64 + c)*136 + pi) = v;
  }
}

// ---------------------------------------------------------------------------
// attn: full-K flash attention with INTRA-BLOCK split-K (no global partials,
// no fences, no combine dispatch -- R2 lesson).
// Grid (64 qtiles, 8 batch) = 512 blocks; block = 256 thr = 4 waves:
// wave (qg, kh) = (w&1, w>>1): q-group qg owns 32 queries, key-half kh owns
// 2048 keys (16 tiles of 128). Two independent double-buffered tile streams
// in dynamic LDS (2 x 2 x 19456 = 77824 B; 2 blocks/CU -> 8 waves/CU =
// 2 waves/SIMD, the measured VALU-saturation plateau from R0).
// One barrier per tile: barrier (drains tile-t loads, both streams) ->
// issue tile-t+1 loads -> compute tile t.
// l is accumulated via a ones-column PV MFMA (B-frag = 1.0 at col 0):
// removes the 16-add serial l_run chain and makes numerator/denominator use
// identical bf16-truncated P. End: kh=1 waves pass o/l partials to kh=0
// waves through LDS; kh=0 normalizes and writes out = gamma*o/l + x.
// ---------------------------------------------------------------------------
__global__ __launch_bounds__(256, 2) void attn_kernel(
    const unsigned short* __restrict__ f_b, const unsigned short* __restrict__ g_b,
    const unsigned short* __restrict__ h_p,
    const float* __restrict__ x, const float* __restrict__ gamma_p,
    float* __restrict__ out)
{
  extern __shared__ char smem[];   // 77824 B: stream kh at kh*38912, buf bi at bi*19456

  const int t = threadIdx.x;
  const int w = t >> 6, lane = t & 63, l31 = lane & 31, a = lane >> 5;
  const int qg = w & 1, kh = w >> 1;
  const int qb = blockIdx.x, b = blockIdx.y;
  const int q0w = qb*64 + qg*32;

  // g B-frag: n = q = l31, k = a*8+j ; real only at a=0 (K=8 zero-padded)
  bf16x8 gfv;
  {
    bf16x8 gv = *(const bf16x8*)(g_b + ((long)b*4096 + q0w + l31)*8);
    bf16x8 z = {};
    gfv = (a == 0) ? gv : z;
  }
  // ones B-frag (col 0 only): accumulates l = sum_k P via the PV MFMA
  bf16x8 bhl;
  {
    union { unsigned short s[8]; bf16x8 v; } o8;
    #pragma unroll
    for (int j = 0; j < 8; ++j) o8.s[j] = 0x3F80;   // bf16 1.0
    bf16x8 z = {};
    bhl = (l31 == 0) ? o8.v : z;
  }

  f32x16 oacc[2], ol;
  { f32x16 z = {}; oacc[0] = z; oacc[1] = z; ol = z; }

  const char* hp_b = (const char*)h_p + (long)b*32*17408;
  const char* fb_b = (const char*)f_b + (long)b*4096*16;
  char* sbase = smem + kh*38912;

  // stage stream-kh tile ktl (global tile kh*16+ktl) into buffer bi.
  // 19456 B = 19 chunks of 1024; the stream's two waves split odd/even.
  auto stage = [&](int bi, int ktl) {
    const int kt = kh*16 + ktl;
    const char* hsrc = hp_b + (long)kt*17408;
    const char* fsrc = fb_b + (long)kt*2048;
    char* dst = sbase + bi*19456;
    #pragma unroll
    for (int i = 0; i < 10; ++i) {
      const int c = i*2 + qg;
      if (c < 19) {
        const int off = c*1024;
        const char* src = (off < 17408) ? (hsrc + off) : (fsrc + (off - 17408));
        gload_lds16(src + lane*16, dst + off);
      }
    }
  };

  stage(0, 0);

  for (int ktl = 0; ktl < 16; ++ktl) {
    __syncthreads();                     // drains tile-ktl loads (both streams)
    if (ktl < 15) stage((ktl + 1) & 1, ktl + 1);

    const unsigned short* hts = (const unsigned short*)(sbase + (ktl & 1)*19456);
    const unsigned short* fts = hts + 8704;   // f block at byte 17408

    #pragma unroll
    for (int mt = 0; mt < 4; ++mt) {
      // S^T sub-tile: keys mt*32.. (storage order) x 32 queries
      bf16x8 afv = *(const bf16x8*)&fts[(mt*32 + l31)*8];
      f32x16 zz = {};
      f32x16 sc = __builtin_amdgcn_mfma_f32_32x32x16_bf16(afv, gfv, zz, 0, 0, 0);

      #pragma unroll
      for (int half = 0; half < 2; ++half) {
        const int s = mt*2 + half;       // PV K-step: contraction k in [16s,16s+16)
        bf16x8 bh0 = *(const bf16x8*)&hts[(l31)*136      + s*16 + a*8];
        bf16x8 bh1 = *(const bf16x8*)&hts[(32 + l31)*136 + s*16 + a*8];
        union { unsigned int u[4]; bf16x8 v; } ap;
        #pragma unroll
        for (int j = 0; j < 4; ++j) {
          float ea = exp2_native(sc[half*8 + 2*j]);      // g pre-scaled by log2e
          float eb = exp2_native(sc[half*8 + 2*j + 1]);
          ap.u[j] = pack_trunc_f(ea, eb);
        }
        oacc[0] = __builtin_amdgcn_mfma_f32_32x32x16_bf16(ap.v, bh0, oacc[0], 0, 0, 0);
        oacc[1] = __builtin_amdgcn_mfma_f32_32x32x16_bf16(ap.v, bh1, oacc[1], 0, 0, 0);
        ol      = __builtin_amdgcn_mfma_f32_32x32x16_bf16(ap.v, bhl, ol,      0, 0, 0);
      }
    }
  }

  // ---- intra-block split-K combine (LDS), then epilogue by kh=0 waves ----
  __syncthreads();                       // all compute done; streams reusable
  float* cb = (float*)smem;              // combine region: 2*64*48*4 = 24576 B
  if (kh == 1) {
    float* d = cb + (qg*64 + lane)*48;
    #pragma unroll
    for (int r = 0; r < 16; ++r) {
      d[r] = oacc[0][r]; d[16 + r] = oacc[1][r]; d[32 + r] = ol[r];
    }
  }
  __syncthreads();
  if (kh == 0) {
    const float* sp = cb + (qg*64 + lane)*48;
    #pragma unroll
    for (int r = 0; r < 16; ++r) {
      oacc[0][r] += sp[r]; oacc[1][r] += sp[16 + r]; ol[r] += sp[32 + r];
    }

    const float gamma = gamma_p[0];
    const float* xb = x + ((long)b*4096 + q0w)*64;
    float* ob = out + ((long)b*4096 + q0w)*64;

    #pragma unroll
    for (int r = 0; r < 16; ++r) {
      const int q = (r & 3) + 8*(r >> 2) + 4*a;     // C row for this acc reg
      // l for row q lives in col-0 lane of this 32-half (lane 0 / lane 32)
      const float lq = __shfl(ol[r], lane & 32);
      const float s = gamma / lq;
      #pragma unroll
      for (int nt = 0; nt < 2; ++nt) {
        const long idx = (long)q*64 + nt*32 + l31;  // col c = nt*32+l31
        ob[idx] = fmaf(s, oacc[nt][r], xb[idx]);
      }
    }
  }
}

extern "C" void kernel_launch(void* const* d_in, const int* in_sizes, int n_in,
                              void* d_out, int out_size, void* d_ws, size_t ws_size,
                              hipStream_t stream) {
  const float* x  = (const float*)d_in[0];
  const float* kf = (const float*)d_in[1];
  const float* kg = (const float*)d_in[2];
  const float* kh = (const float*)d_in[3];
  const float* gamma = (const float*)d_in[4];
  float* out = (float*)d_out;

  char* ws = (char*)d_ws;
  unsigned short* h_p = (unsigned short*)ws;                  // 8*32*64*136*2 = 4,456,448
  unsigned short* f_b = (unsigned short*)(ws + 4456448);      // 524,288
  unsigned short* g_b = (unsigned short*)(ws + 4980736);      // 524,288

  proj_kernel<<<512, 256, 0, stream>>>(x, kf, kg, kh, f_b, g_b, h_p);
  attn_kernel<<<dim3(64, 8), 256, 77824, stream>>>(f_b, g_b, h_p, x, gamma, out);
}